// Round 14
// baseline (75.595 us; speedup 1.0000x reference)
//
#include <hip/hip_runtime.h>
#include <hip/hip_bf16.h>

typedef short bf16x8 __attribute__((ext_vector_type(8)));
typedef float f32x4  __attribute__((ext_vector_type(4)));
typedef int   i32x4  __attribute__((ext_vector_type(4)));

union fragU { f32x4 f; bf16x8 b; uint4 q; uint u[4]; };

// RNE f32->bf16 (pre-kernels only)
__device__ inline ushort f2bf(float f) {
    union { float f; uint u; } v; v.f = f;
    uint r = (v.u + 0x7FFFu + ((v.u >> 16) & 1u)) >> 16;
    return (ushort)r;
}
__device__ inline uint packbf(float a, float b) {
    return (uint)f2bf(a) | ((uint)f2bf(b) << 16);
}
// hot path: single-instruction RNE pack
__device__ inline uint cvtpk(float lo, float hi) {
    uint r;
    asm("v_cvt_pk_bf16_f32 %0, %1, %2" : "=v"(r) : "v"(lo), "v"(hi));
    return r;
}

// ---- pre-kernel A: pack x rows: [f0..f4, 1.0, 0, 0] bf16; row N = zeros ----
__global__ __launch_bounds__(256) void pack_x_kernel(
    const float* __restrict__ x, uint4* __restrict__ xp, int N)
{
    int i = blockIdx.x * blockDim.x + threadIdx.x;
    if (i > N) return;
    uint4 o = {0u, 0u, 0u, 0u};
    if (i < N) {
        const float* r = x + (size_t)i * 5;
        o.x = packbf(r[0], r[1]);
        o.y = packbf(r[2], r[3]);
        o.z = packbf(r[4], 1.0f);   // slot 5 = 1.0 : bias enabler
    }
    xp[i] = o;
}

// ---- pre-kernel B: per-lane fragment table (14 chunks x 64 lanes x 16B) ----
// chunk 0..3  : W1^T A-frags (EF k-layout, b1 at k=5, h1[50]:=1 enabler)
// chunk 4..11 : W2^T A-frags, formal-K perm sigma; hid1==50 := b2
// chunk 12..13: W3 A-frags (row 0 only), same sigma on k
__global__ __launch_bounds__(64) void pack_w_kernel(
    const float* __restrict__ W1, const float* __restrict__ b1,
    const float* __restrict__ W2, const float* __restrict__ b2,
    const float* __restrict__ W3, uint4* __restrict__ tab)
{
    const int lane = threadIdx.x;       // one wave
    const int c = lane & 15;
    const int g = lane >> 4;

    union { ushort s[8]; uint4 q; } u;
    #pragma unroll
    for (int mt = 0; mt < 4; ++mt) {
        #pragma unroll
        for (int d = 0; d < 8; ++d) {
            int k = 8 * g + d;
            int j = 16 * mt + c;
            float v = 0.f;
            if (j < 50) {
                if (k < 5)                 v = W1[k * 50 + j];
                else if (k == 5)           v = b1[j];
                else if (k >= 8 && k < 13) v = W1[(k - 3) * 50 + j];
            } else if (j == 50 && k == 5)  v = 1.0f;
            u.s[d] = f2bf(v);
        }
        tab[mt * 64 + lane] = u.q;
    }
    #pragma unroll
    for (int t = 0; t < 2; ++t) {
        #pragma unroll
        for (int mt = 0; mt < 4; ++mt) {
            #pragma unroll
            for (int d = 0; d < 8; ++d) {
                int hid1 = 16 * (2 * t + (d >> 2)) + 4 * g + (d & 3);
                int j    = 16 * mt + c;
                float v = 0.f;
                if (j < 50) {
                    if (hid1 < 50)       v = W2[hid1 * 50 + j];
                    else if (hid1 == 50) v = b2[j];
                }
                u.s[d] = f2bf(v);
            }
            tab[(4 + t * 4 + mt) * 64 + lane] = u.q;
        }
    }
    #pragma unroll
    for (int t = 0; t < 2; ++t) {
        #pragma unroll
        for (int d = 0; d < 8; ++d) {
            int hid = 16 * (2 * t + (d >> 2)) + 4 * g + (d & 3);
            float v = (c == 0 && hid < 50) ? W3[hid] : 0.f;
            u.s[d] = f2bf(v);
        }
        tab[(12 + t) * 64 + lane] = u.q;
    }
}

// ---- main: 128 contiguous edges/wave (8 jobs); lane c of job j owns edge
//      base + c*8 + j  ->  idx loads become 2x dwordx4/lane; gathers are an
//      8-deep monotone FIFO; idx double-buffered across batches ----
__global__ __launch_bounds__(256, 3) void edge_mlp_mfma11(
    const uint4* __restrict__ xp,
    const uint4* __restrict__ wtab,
    const int* __restrict__ ei,
    const float* __restrict__ b3,
    float* __restrict__ out, int E, int NB)
{
    const int tid  = threadIdx.x;
    const int w    = tid >> 6;
    const int lane = tid & 63;
    const int c    = lane & 15;
    const int g    = lane >> 4;
    const int G    = gridDim.x;

    // one-time coalesced fragment load, then PIN in registers
    fragU w1f[4], w2f[8], w3f[2];
    #pragma unroll
    for (int i = 0; i < 4; ++i) w1f[i].q = wtab[i * 64 + lane];
    #pragma unroll
    for (int i = 0; i < 8; ++i) w2f[i].q = wtab[(4 + i) * 64 + lane];
    #pragma unroll
    for (int i = 0; i < 2; ++i) w3f[i].q = wtab[(12 + i) * 64 + lane];
    asm volatile("" :
        "+v"(w1f[0].f), "+v"(w1f[1].f), "+v"(w1f[2].f), "+v"(w1f[3].f),
        "+v"(w2f[0].f), "+v"(w2f[1].f), "+v"(w2f[2].f), "+v"(w2f[3].f),
        "+v"(w2f[4].f), "+v"(w2f[5].f), "+v"(w2f[6].f), "+v"(w2f[7].f),
        "+v"(w3f[0].f), "+v"(w3f[1].f));

    const float b3s = b3[0];
    const bool e_al = ((E & 3) == 0);     // dwordx4 alignment of row g=1

    // batched index load: lane (c, g<2) gets the 8 consecutive indices for its
    // 8 jobs (edges base + c*8 + 0..7) as two dwordx4
    auto LOAD_IDX = [&](int bt_, i32x4& a, i32x4& b) {
        a = i32x4{0, 0, 0, 0};
        b = i32x4{0, 0, 0, 0};
        int bc = (bt_ < NB) ? bt_ : (NB - 1);
        int base = bc * 512 + w * 128;
        if (g < 2) {
            if (e_al && base + 128 <= E) {
                const i32x4* p = (const i32x4*)(ei + (size_t)g * (size_t)E + base + c * 8);
                a = __builtin_nontemporal_load(p);
                b = __builtin_nontemporal_load(p + 1);
            } else {
                int t[8];
                #pragma unroll
                for (int jj = 0; jj < 8; ++jj) {
                    int e = base + c * 8 + jj;
                    if (e >= E) e = 0;
                    t[jj] = ei[(size_t)g * (size_t)E + (size_t)e];
                }
                a = i32x4{t[0], t[1], t[2], t[3]};
                b = i32x4{t[4], t[5], t[6], t[7]};
            }
        }
    };

    int bt = blockIdx.x;
    if (bt >= NB) return;

    i32x4 iaC, ibC, iaN, ibN;
    LOAD_IDX(bt, iaC, ibC);               // prologue (serial once)

    for (; bt < NB; bt += G) {
        LOAD_IDX(bt + G, iaN, ibN);       // next batch's indices: full batch of slack

        int idxs[8] = {iaC[0], iaC[1], iaC[2], iaC[3], ibC[0], ibC[1], ibC[2], ibC[3]};

        // ---- 8 gathers, monotone FIFO ----
        fragU f[8];
        #pragma unroll
        for (int j = 0; j < 8; ++j) {
            uint4 q = {0u, 0u, 0u, 0u};
            if (g < 2) q = xp[idxs[j]];
            f[j].q = q;
        }

        const int base = bt * 512 + w * 128;

        // ---- 8 computes; compute j waits only on gather j (counted vmcnt) ----
        #pragma unroll
        for (int j = 0; j < 8; ++j) {
            __builtin_amdgcn_s_setprio(1);
            // layer 1 (+b1 folded)
            f32x4 hT[4];
            #pragma unroll
            for (int mt = 0; mt < 4; ++mt) {
                f32x4 z = {0.f, 0.f, 0.f, 0.f};
                hT[mt] = __builtin_amdgcn_mfma_f32_16x16x32_bf16(w1f[mt].b, f[j].b, z, 0, 0, 0);
            }
            fragU bB0, bB1;
            #pragma unroll
            for (int mt = 0; mt < 2; ++mt) {
                bB0.u[2*mt]   = cvtpk(fmaxf(hT[mt][0], 0.f),   fmaxf(hT[mt][1], 0.f));
                bB0.u[2*mt+1] = cvtpk(fmaxf(hT[mt][2], 0.f),   fmaxf(hT[mt][3], 0.f));
                bB1.u[2*mt]   = cvtpk(fmaxf(hT[2+mt][0], 0.f), fmaxf(hT[2+mt][1], 0.f));
                bB1.u[2*mt+1] = cvtpk(fmaxf(hT[2+mt][2], 0.f), fmaxf(hT[2+mt][3], 0.f));
            }
            // layer 2 (+b2 folded)
            f32x4 h2T[4];
            #pragma unroll
            for (int mt = 0; mt < 4; ++mt) {
                f32x4 z = {0.f, 0.f, 0.f, 0.f};
                h2T[mt] = __builtin_amdgcn_mfma_f32_16x16x32_bf16(w2f[mt].b,     bB0.b, z, 0, 0, 0);
                h2T[mt] = __builtin_amdgcn_mfma_f32_16x16x32_bf16(w2f[4 + mt].b, bB1.b, h2T[mt], 0, 0, 0);
            }
            fragU cB0, cB1;
            #pragma unroll
            for (int mt = 0; mt < 2; ++mt) {
                cB0.u[2*mt]   = cvtpk(fmaxf(h2T[mt][0], 0.f),   fmaxf(h2T[mt][1], 0.f));
                cB0.u[2*mt+1] = cvtpk(fmaxf(h2T[mt][2], 0.f),   fmaxf(h2T[mt][3], 0.f));
                cB1.u[2*mt]   = cvtpk(fmaxf(h2T[2+mt][0], 0.f), fmaxf(h2T[2+mt][1], 0.f));
                cB1.u[2*mt+1] = cvtpk(fmaxf(h2T[2+mt][2], 0.f), fmaxf(h2T[2+mt][3], 0.f));
            }
            // layer 3 as MFMA: C row 0 = W3 . relu(h2)
            f32x4 z3 = {0.f, 0.f, 0.f, 0.f};
            f32x4 o3 = __builtin_amdgcn_mfma_f32_16x16x32_bf16(w3f[0].b, cB0.b, z3, 0, 0, 0);
            o3 = __builtin_amdgcn_mfma_f32_16x16x32_bf16(w3f[1].b, cB1.b, o3, 0, 0, 0);
            __builtin_amdgcn_s_setprio(0);

            if (g == 0) {                 // C row 0 -> lanes 0..15, reg 0
                int e = base + c * 8 + j;
                if (e < E) {
                    float ex = __expf(-(o3[0] + b3s));
                    float sg = __builtin_amdgcn_rcpf(1.f + ex);
                    __builtin_nontemporal_store(sg, &out[e]);
                }
            }
        }

        iaC = iaN; ibC = ibN;
    }
}

extern "C" void kernel_launch(void* const* d_in, const int* in_sizes, int n_in,
                              void* d_out, int out_size, void* d_ws, size_t ws_size,
                              hipStream_t stream) {
    const float* x  = (const float*)d_in[0];
    const int*   ei = (const int*)d_in[1];
    const float* W1 = (const float*)d_in[2];
    const float* b1 = (const float*)d_in[3];
    const float* W2 = (const float*)d_in[4];
    const float* b2 = (const float*)d_in[5];
    const float* W3 = (const float*)d_in[6];
    const float* b3 = (const float*)d_in[7];
    float* out = (float*)d_out;

    int E = in_sizes[1] / 2;      // edge_index is [2, E]
    int N = in_sizes[0] / 5;      // nodes

    uint4* wtab = (uint4*)d_ws;                    // 14 KB fragment table
    uint4* xp   = (uint4*)((char*)d_ws + 16384);   // (N+1) * 16 B packed x

    pack_w_kernel<<<1, 64, 0, stream>>>(W1, b1, W2, b2, W3, wtab);
    pack_x_kernel<<<(N + 1 + 255) / 256, 256, 0, stream>>>(x, xp, N);

    int NB = (E + 511) / 512;                      // 512 edges per block-batch
    int grid = NB < 2048 ? NB : 2048;
    edge_mlp_mfma11<<<grid, 256, 0, stream>>>(xp, wtab, ei, b3, out, E, NB);
}

// Round 15
// 65.821 us; speedup vs baseline: 1.1485x; 1.1485x over previous
//
#include <hip/hip_runtime.h>
#include <hip/hip_bf16.h>

typedef short bf16x8 __attribute__((ext_vector_type(8)));
typedef float f32x4  __attribute__((ext_vector_type(4)));
typedef float f32x16 __attribute__((ext_vector_type(16)));

union fragU { f32x4 f; bf16x8 b; uint4 q; uint u[4]; };

// RNE f32->bf16 (pre-kernels only)
__device__ inline ushort f2bf(float f) {
    union { float f; uint u; } v; v.f = f;
    uint r = (v.u + 0x7FFFu + ((v.u >> 16) & 1u)) >> 16;
    return (ushort)r;
}
__device__ inline uint packbf(float a, float b) {
    return (uint)f2bf(a) | ((uint)f2bf(b) << 16);
}
// hot path: single-instruction RNE pack
__device__ inline uint cvtpk(float lo, float hi) {
    uint r;
    asm("v_cvt_pk_bf16_f32 %0, %1, %2" : "=v"(r) : "v"(lo), "v"(hi));
    return r;
}

// ---- pre-kernel A: pack x rows: [f0..f4, 1.0, 0, 0] bf16 ----
__global__ __launch_bounds__(256) void pack_x_kernel(
    const float* __restrict__ x, uint4* __restrict__ xp, int N)
{
    int i = blockIdx.x * blockDim.x + threadIdx.x;
    if (i >= N) return;
    const float* r = x + (size_t)i * 5;
    uint4 o;
    o.x = packbf(r[0], r[1]);
    o.y = packbf(r[2], r[3]);
    o.z = packbf(r[4], 1.0f);    // slot 5 = 1.0 : bias enabler
    o.w = 0u;                    // slots 6,7 = 0
    xp[i] = o;
}

// ---- pre-kernel B: per-lane fragment table for 32x32x16 layout ----
// A-frag (32x32x16): row = lane&31, k = 8*(lane>>5)+d.  C: col=lane&31,
// row = (reg&3)+8*(reg>>2)+4*(lane>>5) (+32*T for row-tile T).
// chunk 0..1  : W1ext^T A-frags, tile T (EF k-layout: 0..4 src, 5=1.0->b1,
//               8..12 tgt, rest 0; j==50,k==5 -> 1.0 enabler for b2)
// chunk 2..9  : W2ext^T A-frags [T][s], k_global=16s+8hi+d; kg==50 -> b2
// chunk 10..17: W3 f32x4 [T][rq], value for C reg=4rq+rr's row
__global__ __launch_bounds__(64) void pack_w_kernel(
    const float* __restrict__ W1, const float* __restrict__ b1,
    const float* __restrict__ W2, const float* __restrict__ b2,
    const float* __restrict__ W3, uint4* __restrict__ tab)
{
    const int lane = threadIdx.x;       // one wave
    const int col  = lane & 31;
    const int hi   = lane >> 5;

    union { ushort s[8]; uint4 q; } u;
    #pragma unroll
    for (int T = 0; T < 2; ++T) {
        #pragma unroll
        for (int d = 0; d < 8; ++d) {
            int k = 8 * hi + d;
            int j = 32 * T + col;
            float v = 0.f;
            if (j < 50) {
                if (k < 5)                 v = W1[k * 50 + j];
                else if (k == 5)           v = b1[j];
                else if (k >= 8 && k < 13) v = W1[(k - 3) * 50 + j];
            } else if (j == 50 && k == 5)  v = 1.0f;
            u.s[d] = f2bf(v);
        }
        tab[T * 64 + lane] = u.q;
    }
    #pragma unroll
    for (int T = 0; T < 2; ++T) {
        #pragma unroll
        for (int s = 0; s < 4; ++s) {
            #pragma unroll
            for (int d = 0; d < 8; ++d) {
                int kg = 16 * s + 8 * hi + d;
                int j  = 32 * T + col;
                float v = 0.f;
                if (j < 50) {
                    if (kg < 50)       v = W2[kg * 50 + j];
                    else if (kg == 50) v = b2[j];
                }
                u.s[d] = f2bf(v);
            }
            tab[(2 + T * 4 + s) * 64 + lane] = u.q;
        }
    }
    union { float f[4]; uint4 q; } wq;
    #pragma unroll
    for (int T = 0; T < 2; ++T) {
        #pragma unroll
        for (int rq = 0; rq < 4; ++rq) {
            #pragma unroll
            for (int rr = 0; rr < 4; ++rr) {
                int reg = 4 * rq + rr;
                int row = (reg & 3) + 8 * (reg >> 2) + 4 * hi + 32 * T;
                wq.f[rr] = (row < 50) ? W3[row] : 0.f;
            }
            tab[(10 + T * 4 + rq) * 64 + lane] = wq.q;
        }
    }
}

// ---- main: 32 edges/wave-job via 32x32x16 MFMA; every lane gathers
//      (col=edge, hi=src/tgt); permlane32_swap interface; VALU layer-3 dot ----
__global__ __launch_bounds__(256, 3) void edge_mlp_mfma12(
    const uint4* __restrict__ xp,
    const uint4* __restrict__ wtab,
    const int* __restrict__ ei,
    const float* __restrict__ b3,
    float* __restrict__ out, int E, int NT)
{
    const int tid  = threadIdx.x;
    const int w    = tid >> 6;
    const int lane = tid & 63;
    const int col  = lane & 31;
    const int hi   = lane >> 5;
    const int G    = gridDim.x;

    // one-time coalesced fragment load, then PIN in registers
    fragU w1f[2], w2f[8], w3q[8];
    #pragma unroll
    for (int i = 0; i < 2; ++i) w1f[i].q = wtab[i * 64 + lane];
    #pragma unroll
    for (int i = 0; i < 8; ++i) w2f[i].q = wtab[(2 + i) * 64 + lane];
    #pragma unroll
    for (int i = 0; i < 8; ++i) w3q[i].q = wtab[(10 + i) * 64 + lane];
    asm volatile("" :
        "+v"(w1f[0].f), "+v"(w1f[1].f),
        "+v"(w2f[0].f), "+v"(w2f[1].f), "+v"(w2f[2].f), "+v"(w2f[3].f),
        "+v"(w2f[4].f), "+v"(w2f[5].f), "+v"(w2f[6].f), "+v"(w2f[7].f),
        "+v"(w3q[0].f), "+v"(w3q[1].f), "+v"(w3q[2].f), "+v"(w3q[3].f),
        "+v"(w3q[4].f), "+v"(w3q[5].f), "+v"(w3q[6].f), "+v"(w3q[7].f));

    const float b3s = b3[0];

    // index for tile t: lane (col, hi) -> ei[hi*E + t*128 + w*32 + col]
    auto LOAD_IDX = [&](int t_) -> int {
        int tc = (t_ < NT) ? t_ : (NT - 1);
        int e = tc * 128 + w * 32 + col;
        if (e >= E) e = 0;
        return ei[(size_t)hi * (size_t)E + (size_t)e];
    };

    const f32x16 z16 = {0.f,0.f,0.f,0.f, 0.f,0.f,0.f,0.f,
                        0.f,0.f,0.f,0.f, 0.f,0.f,0.f,0.f};

    int t = blockIdx.x;
    if (t >= NT) return;

    // 2-deep decoupled pipeline prologue
    fragU f0; f0.q = xp[LOAD_IDX(t)];
    int idx1 = LOAD_IDX(t + G);

    for (; t < NT; t += G) {
        fragU f1; f1.q = xp[idx1];      // gather for t+G (resident address)
        idx1 = LOAD_IDX(t + 2 * G);     // idx for t+2G (independent)

        // ---- layer 1 (+b1 folded): 2 row-tiles of 32x32x16 ----
        f32x16 c1_0 = __builtin_amdgcn_mfma_f32_32x32x16_bf16(w1f[0].b, f0.b, z16, 0, 0, 0);
        f32x16 c1_1 = __builtin_amdgcn_mfma_f32_32x32x16_bf16(w1f[1].b, f0.b, z16, 0, 0, 0);

        // ---- interface: relu + cvt_pk -> 16 words; word[T][k] covers rows
        //      (8m+2n+4hi, +1), m=4T+(k>>1), n=k&1 ----
        uint word[2][8];
        #pragma unroll
        for (int k = 0; k < 8; ++k) {
            word[0][k] = cvtpk(fmaxf(c1_0[2*k], 0.f), fmaxf(c1_0[2*k+1], 0.f));
            word[1][k] = cvtpk(fmaxf(c1_1[2*k], 0.f), fmaxf(c1_1[2*k+1], 0.f));
        }
        // permlane32_swap: D=word[m=2s], S=word[m=2s+1] (m -> T=m>>2, kk=2*(m&3)+n)
        // After swap: D'={D.lo,S.lo} -> X[s][n], S'={D.hi,S.hi} -> Y[s][n];
        // Bfrag[s] = {X0,X1,Y0,Y1} gives k=16s+8hi+d identity order.
        fragU bf[4];
        #pragma unroll
        for (int s = 0; s < 4; ++s) {
            #pragma unroll
            for (int n = 0; n < 2; ++n) {
                const int mD = 2 * s, mS = 2 * s + 1;
                uint D = word[mD >> 2][2 * (mD & 3) + n];
                uint S = word[mS >> 2][2 * (mS & 3) + n];
                asm volatile("v_permlane32_swap_b32 %0, %1" : "+v"(D), "+v"(S));
                bf[s].u[n]     = D;
                bf[s].u[2 + n] = S;
            }
        }

        // ---- layer 2 (+b2 folded): 2 row-tiles x 4 K-slices, accumulate ----
        f32x16 c2_0 = z16, c2_1 = z16;
        #pragma unroll
        for (int s = 0; s < 4; ++s) {
            c2_0 = __builtin_amdgcn_mfma_f32_32x32x16_bf16(w2f[s].b,     bf[s].b, c2_0, 0, 0, 0);
            c2_1 = __builtin_amdgcn_mfma_f32_32x32x16_bf16(w2f[4 + s].b, bf[s].b, c2_1, 0, 0, 0);
        }

        // ---- layer 3: in-register relu-dot with W3, cross-half reduce ----
        float p = 0.f;
        #pragma unroll
        for (int reg = 0; reg < 16; ++reg) {
            p = fmaf(fmaxf(c2_0[reg], 0.f), w3q[reg >> 2].f[reg & 3], p);
            p = fmaf(fmaxf(c2_1[reg], 0.f), w3q[4 + (reg >> 2)].f[reg & 3], p);
        }
        p += __shfl_xor(p, 32);

        if (hi == 0) {                    // lanes 0..31 store 32 edges, coalesced
            int e = t * 128 + w * 32 + col;
            if (e < E) {
                float ex = __expf(-(p + b3s));
                out[e] = __builtin_amdgcn_rcpf(1.f + ex);
            }
        }

        f0 = f1;
    }
}

extern "C" void kernel_launch(void* const* d_in, const int* in_sizes, int n_in,
                              void* d_out, int out_size, void* d_ws, size_t ws_size,
                              hipStream_t stream) {
    const float* x  = (const float*)d_in[0];
    const int*   ei = (const int*)d_in[1];
    const float* W1 = (const float*)d_in[2];
    const float* b1 = (const float*)d_in[3];
    const float* W2 = (const float*)d_in[4];
    const float* b2 = (const float*)d_in[5];
    const float* W3 = (const float*)d_in[6];
    const float* b3 = (const float*)d_in[7];
    float* out = (float*)d_out;

    int E = in_sizes[1] / 2;      // edge_index is [2, E]
    int N = in_sizes[0] / 5;      // nodes

    uint4* wtab = (uint4*)d_ws;                    // 18 KB fragment table
    uint4* xp   = (uint4*)((char*)d_ws + 32768);   // N * 16 B packed x

    pack_w_kernel<<<1, 64, 0, stream>>>(W1, b1, W2, b2, W3, wtab);
    pack_x_kernel<<<(N + 255) / 256, 256, 0, stream>>>(x, xp, N);

    int NT = (E + 127) / 128;                      // 128 edges per block-tile
    int grid = NT < 2048 ? NT : 2048;
    edge_mlp_mfma12<<<grid, 256, 0, stream>>>(xp, wtab, ei, b3, out, E, NT);
}

// Round 16
// 65.812 us; speedup vs baseline: 1.1487x; 1.0001x over previous
//
#include <hip/hip_runtime.h>
#include <hip/hip_bf16.h>

typedef short bf16x8 __attribute__((ext_vector_type(8)));
typedef float f32x4  __attribute__((ext_vector_type(4)));
typedef float f32x16 __attribute__((ext_vector_type(16)));

union fragU { f32x4 f; bf16x8 b; uint4 q; uint u[4]; };

// RNE f32->bf16 (pre-kernels only)
__device__ inline ushort f2bf(float f) {
    union { float f; uint u; } v; v.f = f;
    uint r = (v.u + 0x7FFFu + ((v.u >> 16) & 1u)) >> 16;
    return (ushort)r;
}
__device__ inline uint packbf(float a, float b) {
    return (uint)f2bf(a) | ((uint)f2bf(b) << 16);
}
// hot path: single-instruction RNE pack
__device__ inline uint cvtpk(float lo, float hi) {
    uint r;
    asm("v_cvt_pk_bf16_f32 %0, %1, %2" : "=v"(r) : "v"(lo), "v"(hi));
    return r;
}

// ---- pre-kernel A: pack x rows: [f0..f4, 1.0, 0, 0] bf16 ----
__global__ __launch_bounds__(256) void pack_x_kernel(
    const float* __restrict__ x, uint4* __restrict__ xp, int N)
{
    int i = blockIdx.x * blockDim.x + threadIdx.x;
    if (i >= N) return;
    const float* r = x + (size_t)i * 5;
    uint4 o;
    o.x = packbf(r[0], r[1]);
    o.y = packbf(r[2], r[3]);
    o.z = packbf(r[4], 1.0f);    // slot 5 = 1.0 : bias enabler
    o.w = 0u;                    // slots 6,7 = 0
    xp[i] = o;
}

// ---- pre-kernel B: per-lane fragment table for 32x32x16 layout ----
// A-frag (32x32x16): row = lane&31, k = 8*(lane>>5)+d.  C: col=lane&31,
// row = (reg&3)+8*(reg>>2)+4*(lane>>5) (+32*T for row-tile T).
// chunk 0..1  : W1ext^T A-frags, tile T (EF k-layout: 0..4 src, 5=1.0->b1,
//               8..12 tgt, rest 0; j==50,k==5 -> 1.0 enabler for b2)
// chunk 2..9  : W2ext^T A-frags [T][s], kg=16s+8hi+d; kg==50 -> b2
// chunk 10..13: W3 A-frags, slice s (row 0 only): col==0 -> W3[kg], else 0
__global__ __launch_bounds__(64) void pack_w_kernel(
    const float* __restrict__ W1, const float* __restrict__ b1,
    const float* __restrict__ W2, const float* __restrict__ b2,
    const float* __restrict__ W3, uint4* __restrict__ tab)
{
    const int lane = threadIdx.x;       // one wave
    const int col  = lane & 31;
    const int hi   = lane >> 5;

    union { ushort s[8]; uint4 q; } u;
    #pragma unroll
    for (int T = 0; T < 2; ++T) {
        #pragma unroll
        for (int d = 0; d < 8; ++d) {
            int k = 8 * hi + d;
            int j = 32 * T + col;
            float v = 0.f;
            if (j < 50) {
                if (k < 5)                 v = W1[k * 50 + j];
                else if (k == 5)           v = b1[j];
                else if (k >= 8 && k < 13) v = W1[(k - 3) * 50 + j];
            } else if (j == 50 && k == 5)  v = 1.0f;
            u.s[d] = f2bf(v);
        }
        tab[T * 64 + lane] = u.q;
    }
    #pragma unroll
    for (int T = 0; T < 2; ++T) {
        #pragma unroll
        for (int s = 0; s < 4; ++s) {
            #pragma unroll
            for (int d = 0; d < 8; ++d) {
                int kg = 16 * s + 8 * hi + d;
                int j  = 32 * T + col;
                float v = 0.f;
                if (j < 50) {
                    if (kg < 50)       v = W2[kg * 50 + j];
                    else if (kg == 50) v = b2[j];
                }
                u.s[d] = f2bf(v);
            }
            tab[(2 + T * 4 + s) * 64 + lane] = u.q;
        }
    }
    #pragma unroll
    for (int s = 0; s < 4; ++s) {
        #pragma unroll
        for (int d = 0; d < 8; ++d) {
            int kg = 16 * s + 8 * hi + d;
            float v = (col == 0 && kg < 50) ? W3[kg] : 0.f;
            u.s[d] = f2bf(v);
        }
        tab[(10 + s) * 64 + lane] = u.q;
    }
}

// ---- main: 32 edges/wave-job via 32x32x16 MFMA; all-lane gather;
//      permlane32_swap interface reused for BOTH layer interfaces;
//      layer 3 as 4 MFMAs into C row 0 ----
__global__ __launch_bounds__(256, 4) void edge_mlp_mfma13(
    const uint4* __restrict__ xp,
    const uint4* __restrict__ wtab,
    const int* __restrict__ ei,
    const float* __restrict__ b3,
    float* __restrict__ out, int E, int NT)
{
    const int tid  = threadIdx.x;
    const int w    = tid >> 6;
    const int lane = tid & 63;
    const int col  = lane & 31;
    const int hi   = lane >> 5;
    const int G    = gridDim.x;

    // one-time coalesced fragment load, then PIN in registers (14 fragU = 56)
    fragU w1f[2], w2f[8], w3a[4];
    #pragma unroll
    for (int i = 0; i < 2; ++i) w1f[i].q = wtab[i * 64 + lane];
    #pragma unroll
    for (int i = 0; i < 8; ++i) w2f[i].q = wtab[(2 + i) * 64 + lane];
    #pragma unroll
    for (int i = 0; i < 4; ++i) w3a[i].q = wtab[(10 + i) * 64 + lane];
    asm volatile("" :
        "+v"(w1f[0].f), "+v"(w1f[1].f),
        "+v"(w2f[0].f), "+v"(w2f[1].f), "+v"(w2f[2].f), "+v"(w2f[3].f),
        "+v"(w2f[4].f), "+v"(w2f[5].f), "+v"(w2f[6].f), "+v"(w2f[7].f),
        "+v"(w3a[0].f), "+v"(w3a[1].f), "+v"(w3a[2].f), "+v"(w3a[3].f));

    const float b3s = b3[0];

    // index for tile t: lane (col, hi) -> ei[hi*E + t*128 + w*32 + col]
    auto LOAD_IDX = [&](int t_) -> int {
        int tc = (t_ < NT) ? t_ : (NT - 1);
        int e = tc * 128 + w * 32 + col;
        if (e >= E) e = 0;
        return ei[(size_t)hi * (size_t)E + (size_t)e];
    };

    const f32x16 z16 = {0.f,0.f,0.f,0.f, 0.f,0.f,0.f,0.f,
                        0.f,0.f,0.f,0.f, 0.f,0.f,0.f,0.f};

    // relu + pack + permlane32_swap: C-frag pair -> 4 B-frags, k=16s+8hi+d
    auto INTERFACE = [&](const f32x16& c0, const f32x16& c1, fragU* bf) {
        uint word[2][8];
        #pragma unroll
        for (int k = 0; k < 8; ++k) {
            word[0][k] = cvtpk(fmaxf(c0[2*k], 0.f), fmaxf(c0[2*k+1], 0.f));
            word[1][k] = cvtpk(fmaxf(c1[2*k], 0.f), fmaxf(c1[2*k+1], 0.f));
        }
        #pragma unroll
        for (int s = 0; s < 4; ++s) {
            #pragma unroll
            for (int n = 0; n < 2; ++n) {
                const int mD = 2 * s, mS = 2 * s + 1;
                uint D = word[mD >> 2][2 * (mD & 3) + n];
                uint S = word[mS >> 2][2 * (mS & 3) + n];
                asm volatile("v_permlane32_swap_b32 %0, %1" : "+v"(D), "+v"(S));
                bf[s].u[n]     = D;
                bf[s].u[2 + n] = S;
            }
        }
    };

    int t = blockIdx.x;
    if (t >= NT) return;

    // 2-deep decoupled pipeline prologue
    fragU f0; f0.q = xp[LOAD_IDX(t)];
    int idx1 = LOAD_IDX(t + G);

    for (; t < NT; t += G) {
        fragU f1; f1.q = xp[idx1];      // gather for t+G (resident address)
        idx1 = LOAD_IDX(t + 2 * G);     // idx for t+2G (independent)

        // ---- layer 1 (+b1 folded): 2 row-tiles ----
        f32x16 c1_0 = __builtin_amdgcn_mfma_f32_32x32x16_bf16(w1f[0].b, f0.b, z16, 0, 0, 0);
        f32x16 c1_1 = __builtin_amdgcn_mfma_f32_32x32x16_bf16(w1f[1].b, f0.b, z16, 0, 0, 0);

        // ---- interface 1: h1 C-frags -> layer-2 B-frags ----
        fragU bf[4];
        INTERFACE(c1_0, c1_1, bf);

        // ---- layer 2 (+b2 folded): 2 row-tiles x 4 K-slices ----
        f32x16 c2_0 = z16, c2_1 = z16;
        #pragma unroll
        for (int s = 0; s < 4; ++s) {
            c2_0 = __builtin_amdgcn_mfma_f32_32x32x16_bf16(w2f[s].b,     bf[s].b, c2_0, 0, 0, 0);
            c2_1 = __builtin_amdgcn_mfma_f32_32x32x16_bf16(w2f[4 + s].b, bf[s].b, c2_1, 0, 0, 0);
        }

        // ---- interface 2: h2 C-frags -> layer-3 B-frags (same transform) ----
        fragU bf2[4];
        INTERFACE(c2_0, c2_1, bf2);

        // ---- layer 3: 4 MFMAs, W3 in A row 0; result in C row 0 ----
        f32x16 c3 = z16;
        #pragma unroll
        for (int s = 0; s < 4; ++s)
            c3 = __builtin_amdgcn_mfma_f32_32x32x16_bf16(w3a[s].b, bf2[s].b, c3, 0, 0, 0);

        if (hi == 0) {                    // C row 0 -> reg 0, lanes 0..31
            int e = t * 128 + w * 32 + col;
            if (e < E) {
                float ex = __expf(-(c3[0] + b3s));
                out[e] = __builtin_amdgcn_rcpf(1.f + ex);
            }
        }

        f0 = f1;
    }
}

extern "C" void kernel_launch(void* const* d_in, const int* in_sizes, int n_in,
                              void* d_out, int out_size, void* d_ws, size_t ws_size,
                              hipStream_t stream) {
    const float* x  = (const float*)d_in[0];
    const int*   ei = (const int*)d_in[1];
    const float* W1 = (const float*)d_in[2];
    const float* b1 = (const float*)d_in[3];
    const float* W2 = (const float*)d_in[4];
    const float* b2 = (const float*)d_in[5];
    const float* W3 = (const float*)d_in[6];
    const float* b3 = (const float*)d_in[7];
    float* out = (float*)d_out;

    int E = in_sizes[1] / 2;      // edge_index is [2, E]
    int N = in_sizes[0] / 5;      // nodes

    uint4* wtab = (uint4*)d_ws;                    // 14 KB fragment table
    uint4* xp   = (uint4*)((char*)d_ws + 32768);   // N * 16 B packed x

    pack_w_kernel<<<1, 64, 0, stream>>>(W1, b1, W2, b2, W3, wtab);
    pack_x_kernel<<<(N + 255) / 256, 256, 0, stream>>>(x, xp, N);

    int NT = (E + 127) / 128;                      // 128 edges per block-tile
    int grid = NT < 2048 ? NT : 2048;
    edge_mlp_mfma13<<<grid, 256, 0, stream>>>(xp, wtab, ei, b3, out, E, NT);
}

// Round 17
// 65.450 us; speedup vs baseline: 1.1550x; 1.0055x over previous
//
#include <hip/hip_runtime.h>
#include <hip/hip_bf16.h>

typedef short bf16x8 __attribute__((ext_vector_type(8)));
typedef float f32x4  __attribute__((ext_vector_type(4)));
typedef float f32x16 __attribute__((ext_vector_type(16)));

union fragU { f32x4 f; bf16x8 b; uint4 q; uint u[4]; };

// RNE f32->bf16 (pre-kernels only)
__device__ inline ushort f2bf(float f) {
    union { float f; uint u; } v; v.f = f;
    uint r = (v.u + 0x7FFFu + ((v.u >> 16) & 1u)) >> 16;
    return (ushort)r;
}
__device__ inline uint packbf(float a, float b) {
    return (uint)f2bf(a) | ((uint)f2bf(b) << 16);
}
// hot path: single-instruction RNE pack (output forced to arch VGPR)
__device__ inline uint cvtpk(float lo, float hi) {
    uint r;
    asm("v_cvt_pk_bf16_f32 %0, %1, %2" : "=v"(r) : "v"(lo), "v"(hi));
    return r;
}

// ---- pre-kernel A: pack x rows: [f0..f4, 1.0, 0, 0] bf16 ----
__global__ __launch_bounds__(256) void pack_x_kernel(
    const float* __restrict__ x, uint4* __restrict__ xp, int N)
{
    int i = blockIdx.x * blockDim.x + threadIdx.x;
    if (i >= N) return;
    const float* r = x + (size_t)i * 5;
    uint4 o;
    o.x = packbf(r[0], r[1]);
    o.y = packbf(r[2], r[3]);
    o.z = packbf(r[4], 1.0f);    // slot 5 = 1.0 : bias enabler
    o.w = 0u;                    // slots 6,7 = 0
    xp[i] = o;
}

// ---- pre-kernel B: per-lane fragment table for 32x32x16 layout ----
// A-frag (32x32x16): row = lane&31, k = 8*(lane>>5)+d.  C: col=lane&31,
// row = (reg&3)+8*(reg>>2)+4*(lane>>5) (+32*T for row-tile T).
// chunk 0..1  : W1ext^T A-frags, tile T (EF k-layout: 0..4 src, 5=1.0->b1,
//               8..12 tgt, rest 0; j==50,k==5 -> 1.0 enabler for b2)
// chunk 2..9  : W2ext^T A-frags [T][s], kg=16s+8hi+d; kg==50 -> b2
// chunk 10..13: W3 A-frags, slice s (row 0 only): col==0 -> W3[kg], else 0
__global__ __launch_bounds__(64) void pack_w_kernel(
    const float* __restrict__ W1, const float* __restrict__ b1,
    const float* __restrict__ W2, const float* __restrict__ b2,
    const float* __restrict__ W3, uint4* __restrict__ tab)
{
    const int lane = threadIdx.x;       // one wave
    const int col  = lane & 31;
    const int hi   = lane >> 5;

    union { ushort s[8]; uint4 q; } u;
    #pragma unroll
    for (int T = 0; T < 2; ++T) {
        #pragma unroll
        for (int d = 0; d < 8; ++d) {
            int k = 8 * hi + d;
            int j = 32 * T + col;
            float v = 0.f;
            if (j < 50) {
                if (k < 5)                 v = W1[k * 50 + j];
                else if (k == 5)           v = b1[j];
                else if (k >= 8 && k < 13) v = W1[(k - 3) * 50 + j];
            } else if (j == 50 && k == 5)  v = 1.0f;
            u.s[d] = f2bf(v);
        }
        tab[T * 64 + lane] = u.q;
    }
    #pragma unroll
    for (int T = 0; T < 2; ++T) {
        #pragma unroll
        for (int s = 0; s < 4; ++s) {
            #pragma unroll
            for (int d = 0; d < 8; ++d) {
                int kg = 16 * s + 8 * hi + d;
                int j  = 32 * T + col;
                float v = 0.f;
                if (j < 50) {
                    if (kg < 50)       v = W2[kg * 50 + j];
                    else if (kg == 50) v = b2[j];
                }
                u.s[d] = f2bf(v);
            }
            tab[(2 + T * 4 + s) * 64 + lane] = u.q;
        }
    }
    #pragma unroll
    for (int s = 0; s < 4; ++s) {
        #pragma unroll
        for (int d = 0; d < 8; ++d) {
            int kg = 16 * s + 8 * hi + d;
            float v = (col == 0 && kg < 50) ? W3[kg] : 0.f;
            u.s[d] = f2bf(v);
        }
        tab[(10 + s) * 64 + lane] = u.q;
    }
}

// ---- main: 32 edges/wave-job via 32x32x16 MFMA; accumulators FORCED into
//      arch VGPRs via opaque pins (kills v_accvgpr_read/write traffic) ----
__global__ __launch_bounds__(256, 3) void edge_mlp_mfma14(
    const uint4* __restrict__ xp,
    const uint4* __restrict__ wtab,
    const int* __restrict__ ei,
    const float* __restrict__ b3,
    float* __restrict__ out, int E, int NT)
{
    const int tid  = threadIdx.x;
    const int w    = tid >> 6;
    const int lane = tid & 63;
    const int col  = lane & 31;
    const int hi   = lane >> 5;
    const int G    = gridDim.x;

    // one-time coalesced fragment load, then PIN in registers (14 fragU = 56)
    fragU w1f[2], w2f[8], w3a[4];
    #pragma unroll
    for (int i = 0; i < 2; ++i) w1f[i].q = wtab[i * 64 + lane];
    #pragma unroll
    for (int i = 0; i < 8; ++i) w2f[i].q = wtab[(2 + i) * 64 + lane];
    #pragma unroll
    for (int i = 0; i < 4; ++i) w3a[i].q = wtab[(10 + i) * 64 + lane];
    asm volatile("" :
        "+v"(w1f[0].f), "+v"(w1f[1].f),
        "+v"(w2f[0].f), "+v"(w2f[1].f), "+v"(w2f[2].f), "+v"(w2f[3].f),
        "+v"(w2f[4].f), "+v"(w2f[5].f), "+v"(w2f[6].f), "+v"(w2f[7].f),
        "+v"(w3a[0].f), "+v"(w3a[1].f), "+v"(w3a[2].f), "+v"(w3a[3].f));

    // pinned zero tuple: C operand for every first-slice MFMA (no per-iter init)
    f32x16 ztup;
    #pragma unroll
    for (int i = 0; i < 16; ++i) ztup[i] = 0.f;
    asm volatile("" : "+v"(ztup));

    const float b3s = b3[0];

    // index for tile t: lane (col, hi) -> ei[hi*E + t*128 + w*32 + col]
    auto LOAD_IDX = [&](int t_) -> int {
        int tc = (t_ < NT) ? t_ : (NT - 1);
        int e = tc * 128 + w * 32 + col;
        if (e >= E) e = 0;
        return ei[(size_t)hi * (size_t)E + (size_t)e];
    };

    // relu + pack + permlane32_swap: C-frag pair -> 4 B-frags, k=16s+8hi+d
    auto INTERFACE = [&](const f32x16& c0, const f32x16& c1, fragU* bf) {
        uint word[2][8];
        #pragma unroll
        for (int k = 0; k < 8; ++k) {
            word[0][k] = cvtpk(fmaxf(c0[2*k], 0.f), fmaxf(c0[2*k+1], 0.f));
            word[1][k] = cvtpk(fmaxf(c1[2*k], 0.f), fmaxf(c1[2*k+1], 0.f));
        }
        #pragma unroll
        for (int s = 0; s < 4; ++s) {
            #pragma unroll
            for (int n = 0; n < 2; ++n) {
                const int mD = 2 * s, mS = 2 * s + 1;
                uint D = word[mD >> 2][2 * (mD & 3) + n];
                uint S = word[mS >> 2][2 * (mS & 3) + n];
                asm volatile("v_permlane32_swap_b32 %0, %1" : "+v"(D), "+v"(S));
                bf[s].u[n]     = D;
                bf[s].u[2 + n] = S;
            }
        }
    };

    int t = blockIdx.x;
    if (t >= NT) return;

    // 2-deep decoupled pipeline prologue
    fragU f0; f0.q = xp[LOAD_IDX(t)];
    int idx1 = LOAD_IDX(t + G);

    for (; t < NT; t += G) {
        fragU f1; f1.q = xp[idx1];      // gather for t+G (resident address)
        idx1 = LOAD_IDX(t + 2 * G);     // idx for t+2G (independent)

        // ---- layer 1 (+b1 folded): 2 row-tiles; accs pinned to VGPRs ----
        f32x16 c1_0 = __builtin_amdgcn_mfma_f32_32x32x16_bf16(w1f[0].b, f0.b, ztup, 0, 0, 0);
        f32x16 c1_1 = __builtin_amdgcn_mfma_f32_32x32x16_bf16(w1f[1].b, f0.b, ztup, 0, 0, 0);
        asm volatile("" : "+v"(c1_0), "+v"(c1_1));

        // ---- interface 1: h1 C-frags -> layer-2 B-frags ----
        fragU bf[4];
        INTERFACE(c1_0, c1_1, bf);

        // ---- layer 2 (+b2 folded): 2 row-tiles x 4 K-slices ----
        f32x16 c2_0 = __builtin_amdgcn_mfma_f32_32x32x16_bf16(w2f[0].b, bf[0].b, ztup, 0, 0, 0);
        f32x16 c2_1 = __builtin_amdgcn_mfma_f32_32x32x16_bf16(w2f[4].b, bf[0].b, ztup, 0, 0, 0);
        #pragma unroll
        for (int s = 1; s < 4; ++s) {
            c2_0 = __builtin_amdgcn_mfma_f32_32x32x16_bf16(w2f[s].b,     bf[s].b, c2_0, 0, 0, 0);
            c2_1 = __builtin_amdgcn_mfma_f32_32x32x16_bf16(w2f[4 + s].b, bf[s].b, c2_1, 0, 0, 0);
        }
        asm volatile("" : "+v"(c2_0), "+v"(c2_1));

        // ---- interface 2: h2 C-frags -> layer-3 B-frags (same transform) ----
        fragU bf2[4];
        INTERFACE(c2_0, c2_1, bf2);

        // ---- layer 3: 4 MFMAs, W3 in A row 0; result in C row 0 ----
        f32x16 c3 = __builtin_amdgcn_mfma_f32_32x32x16_bf16(w3a[0].b, bf2[0].b, ztup, 0, 0, 0);
        #pragma unroll
        for (int s = 1; s < 4; ++s)
            c3 = __builtin_amdgcn_mfma_f32_32x32x16_bf16(w3a[s].b, bf2[s].b, c3, 0, 0, 0);
        asm volatile("" : "+v"(c3));

        if (hi == 0) {                    // C row 0 -> reg 0, lanes 0..31
            int e = t * 128 + w * 32 + col;
            if (e < E) {
                float ex = __expf(-(c3[0] + b3s));
                out[e] = __builtin_amdgcn_rcpf(1.f + ex);
            }
        }

        f0 = f1;
    }
}

extern "C" void kernel_launch(void* const* d_in, const int* in_sizes, int n_in,
                              void* d_out, int out_size, void* d_ws, size_t ws_size,
                              hipStream_t stream) {
    const float* x  = (const float*)d_in[0];
    const int*   ei = (const int*)d_in[1];
    const float* W1 = (const float*)d_in[2];
    const float* b1 = (const float*)d_in[3];
    const float* W2 = (const float*)d_in[4];
    const float* b2 = (const float*)d_in[5];
    const float* W3 = (const float*)d_in[6];
    const float* b3 = (const float*)d_in[7];
    float* out = (float*)d_out;

    int E = in_sizes[1] / 2;      // edge_index is [2, E]
    int N = in_sizes[0] / 5;      // nodes

    uint4* wtab = (uint4*)d_ws;                    // 14 KB fragment table
    uint4* xp   = (uint4*)((char*)d_ws + 32768);   // N * 16 B packed x

    pack_w_kernel<<<1, 64, 0, stream>>>(W1, b1, W2, b2, W3, wtab);
    pack_x_kernel<<<(N + 255) / 256, 256, 0, stream>>>(x, xp, N);

    int NT = (E + 127) / 128;                      // 128 edges per block-tile
    int grid = NT < 2048 ? NT : 2048;
    edge_mlp_mfma14<<<grid, 256, 0, stream>>>(xp, wtab, ei, b3, out, E, NT);
}